// Round 12
// baseline (140.727 us; speedup 1.0000x reference)
//
#include <hip/hip_runtime.h>
#include <math.h>

// Grid constants from the reference
#define GH 512
#define GW 512
#define GHW (GH * GW)
#define RR 3
#define SH 32            // strip height (R6/R10-proven; SH=16 doubles scan cost)
#define SSHIFT 5
#define NSTRIP (GH / SH) // 16
#define SCAP 1024        // per-strip staged capacity (mean ~580 @ SH=32)
#define THR 1024         // heat threads (16 waves, 1 block/CU at 72KB LDS)
#define GTHR 128         // gather threads per block (2 waves)
#define GCH 1024         // gather points per chunk/block (8 pts/thread)

typedef float f32x4 __attribute__((ext_vector_type(4)));  // nontemporal builtins
// reject HIP_vector_type (R7 compile fail) - use clang ext_vector_type.

// Precision model (validated, absmax 3.9e-3): pure f32 chain, *10.0f voxel
// scale, f32 expf, f32 pose (bit-identical to f64 for identity-rotation
// poses; validated R8). Heat max is order-free (int-bit atomicMax on
// positive floats) => strip/staging order cannot perturb results.
//
// Cost model (fitted R0-R11): T = 21 fixed + 41 ws-fill + Sum(device) + 13/dispatch.
// SETTLED: 2 dispatches (coop +35us R2/R4; software barrier +500us R9 -
// relaxed atomic polls served by non-coherent local XCD L2). Heat: R10/R11
// form = 19.6us, frozen. Gather plateau: THREE designs (scalar-strided R6,
// consec-vec R10, LDS-staged R11) all 28-32us; shared binder = 4.3M random
// heat dword reads = 4.3M distinct L2 lines. All three also shared MLP
// ~6.1K reads-in-flight/CU (LDS-per-point fixed it). R12 discriminator:
// xyz-only 12KB stage + GTHR=128 + 8 pts/thread => MLP ~13.3K/CU (2.2x).
// Drop => latency-bound confirmed; unchanged => L2-transaction-rate floor
// (ROOFLINE: 62us harness + 26us min-dispatch + 20 heat + ~30 gather).

__device__ __forceinline__ void compute_pose(const float* __restrict__ P0,
                                             const float* __restrict__ P1,
                                             float* __restrict__ T) {
    float a00 = P1[0], a01 = P1[1], a02 = P1[2],  t1x = P1[3];
    float a10 = P1[4], a11 = P1[5], a12 = P1[6],  t1y = P1[7];
    float a20 = P1[8], a21 = P1[9], a22 = P1[10], t1z = P1[11];
    float c00 = a11 * a22 - a12 * a21;
    float c01 = a12 * a20 - a10 * a22;
    float c02 = a10 * a21 - a11 * a20;
    float det = a00 * c00 + a01 * c01 + a02 * c02;
    float id = 1.0f / det;
    float r00 = c00 * id;
    float r01 = (a02 * a21 - a01 * a22) * id;
    float r02 = (a01 * a12 - a02 * a11) * id;
    float r10 = c01 * id;
    float r11 = (a00 * a22 - a02 * a20) * id;
    float r12 = (a02 * a10 - a00 * a12) * id;
    float r20 = c02 * id;
    float r21 = (a01 * a20 - a00 * a21) * id;
    float r22 = (a00 * a11 - a01 * a10) * id;

    float b00 = P0[0], b01 = P0[1], b02 = P0[2],  t0x = P0[3];
    float b10 = P0[4], b11 = P0[5], b12 = P0[6],  t0y = P0[7];
    float b20 = P0[8], b21 = P0[9], b22 = P0[10], t0z = P0[11];
    float dx = t0x - t1x, dy = t0y - t1y, dz = t0z - t1z;

    T[0]  = r00 * b00 + r01 * b10 + r02 * b20;
    T[1]  = r00 * b01 + r01 * b11 + r02 * b21;
    T[2]  = r00 * b02 + r01 * b12 + r02 * b22;
    T[3]  = r00 * dx + r01 * dy + r02 * dz;
    T[4]  = r10 * b00 + r11 * b10 + r12 * b20;
    T[5]  = r10 * b01 + r11 * b11 + r12 * b21;
    T[6]  = r10 * b02 + r11 * b12 + r12 * b22;
    T[7]  = r10 * dx + r11 * dy + r12 * dz;
    T[8]  = r20 * b00 + r21 * b10 + r22 * b20;
    T[9]  = r20 * b01 + r21 * b11 + r22 * b21;
    T[10] = r20 * b02 + r21 * b12 + r22 * b22;
    T[11] = r20 * dx + r21 * dy + r22 * dz;
}

__device__ __forceinline__ void voxelize_xyz(float x, float y, float z,
                                             const float* __restrict__ T, // or nullptr
                                             float& px, float& py,
                                             int& ix, int& iy, bool& valid) {
    if (T) {
        float nx = T[0] * x + T[1] * y + T[2] * z + T[3];
        float ny = T[4] * x + T[5] * y + T[6] * z + T[7];
        float nz = T[8] * x + T[9] * y + T[10] * z + T[11];
        x = nx; y = ny; z = nz;
    }
    px = (x - 0.0f) * 10.0f;
    py = (y - (-25.6f)) * 10.0f;
    ix = (int)floorf(px);
    iy = (int)floorf(py);
    valid = (ix >= 0) & (ix < GH) & (iy >= 0) & (iy < GW) &
            (z >= -3.0f) & (z < 3.0f);
}

// Heat kernel: FROZEN (R10/R11 form, ~19.6us). One block per (strip, map, b),
// 1024 threads, 1 block/CU (72KB LDS). Phase A: vec scan (4 pts/thread) +
// early-x reject + wave-aggregated staging; Phase B: n*49 LDS atomicMax
// splat; Phase C: float4 writeback.
__global__ __launch_bounds__(THR)
void heat_strip_kernel(const float* __restrict__ radar0,
                       const float* __restrict__ radar1,
                       const float* __restrict__ pose0,
                       const float* __restrict__ pose1,
                       float* __restrict__ heat0,
                       float* __restrict__ heat1,
                       int B, int M) {
    __shared__ int strip[SH * GW];   // 64 KB
    __shared__ float2 sp[SCAP];      // 8 KB
    __shared__ float Tsh[8][12];
    __shared__ int sn;

    const int tid = threadIdx.x;
    const int lane = tid & 63;
    const int blk = blockIdx.x;
    const int b = blk % B;                 // == XCD id for B=8
    const int map = (blk / B) & 1;
    const int sx = blk / (2 * B);
    const int x0 = sx << SSHIFT;

    if (tid < B) compute_pose(pose0 + tid * 16, pose1 + tid * 16, &Tsh[tid][0]);
    if (tid == 0) sn = 0;
    {
        const int4 z4 = make_int4(0, 0, 0, 0);
        for (int c4 = tid * 4; c4 < SH * GW; c4 += 4 * THR)
            *reinterpret_cast<int4*>(&strip[c4]) = z4;
    }
    __syncthreads();

    const float* radar = map ? radar1 : radar0;
    const float* pb = radar + (size_t)b * M * 6;
    const f32x4* pb4 = reinterpret_cast<const f32x4*>(pb);
    const bool hasT = (map == 0);
    const float* T = &Tsh[b][0];

    const int ng = M >> 2;                 // 4-point groups
    for (int g0 = 0; g0 < ng; g0 += THR) { // uniform bound: ballot reachable
        int g = g0 + tid;
        bool inr = (g < ng);
        float X[4], Y[4], Z[4];
        if (inr) {
            const f32x4* s = pb4 + (size_t)g * 6;
            f32x4 q0 = s[0], q1 = s[1], q2 = s[2];
            f32x4 q3 = s[3], q4 = s[4], q5 = s[5];
            X[0] = q0.x; Y[0] = q0.y; Z[0] = q0.z;
            X[1] = q1.z; Y[1] = q1.w; Z[1] = q2.x;
            X[2] = q3.x; Y[2] = q3.y; Z[2] = q3.z;
            X[3] = q4.z; Y[3] = q4.w; Z[3] = q5.x;
        }
        #pragma unroll
        for (int j = 0; j < 4; j++) {
            bool valid = false;
            float px = 0.0f, py = 0.0f;
            if (inr) {
                float x = X[j], y = Y[j], z = Z[j];
                float nx = hasT ? (T[0] * x + T[1] * y + T[2] * z + T[3]) : x;
                px = (nx - 0.0f) * 10.0f;
                int ix = (int)floorf(px);
                if (ix >= x0 - RR && ix <= x0 + SH - 1 + RR) {
                    float ny = hasT ? (T[4] * x + T[5] * y + T[6] * z + T[7]) : y;
                    float nz = hasT ? (T[8] * x + T[9] * y + T[10] * z + T[11]) : z;
                    py = (ny - (-25.6f)) * 10.0f;
                    int iy = (int)floorf(py);
                    valid = (ix >= 0) & (ix < GH) & (iy >= 0) & (iy < GW) &
                            (nz >= -3.0f) & (nz < 3.0f);
                }
            }
            unsigned long long mask = __ballot(valid);
            if (valid) {
                int leader = __ffsll((long long)mask) - 1;
                int cnt = __popcll(mask);
                int wbase = 0;
                if (lane == leader) wbase = atomicAdd(&sn, cnt);
                wbase = __shfl(wbase, leader);
                int off = __popcll(mask & ((1ull << lane) - 1ull));
                int slot = wbase + off;
                if (slot < SCAP) sp[slot] = make_float2(px, py);
            }
        }
    }
    if (M & 3) {   // scalar remainder (uniform reach)
        int i = (M & ~3) + tid;
        bool valid = false;
        float px = 0.0f, py = 0.0f;
        if (i < M) {
            const float* p = pb + (size_t)i * 6;
            float x = p[0], y = p[1], z = p[2];
            float nx = hasT ? (T[0] * x + T[1] * y + T[2] * z + T[3]) : x;
            px = (nx - 0.0f) * 10.0f;
            int ix = (int)floorf(px);
            if (ix >= x0 - RR && ix <= x0 + SH - 1 + RR) {
                float ny = hasT ? (T[4] * x + T[5] * y + T[6] * z + T[7]) : y;
                float nz = hasT ? (T[8] * x + T[9] * y + T[10] * z + T[11]) : z;
                py = (ny - (-25.6f)) * 10.0f;
                int iy = (int)floorf(py);
                valid = (ix >= 0) & (ix < GH) & (iy >= 0) & (iy < GW) &
                        (nz >= -3.0f) & (nz < 3.0f);
            }
        }
        unsigned long long mask = __ballot(valid);
        if (valid) {
            int leader = __ffsll((long long)mask) - 1;
            int cnt = __popcll(mask);
            int wbase = 0;
            if (lane == leader) wbase = atomicAdd(&sn, cnt);
            wbase = __shfl(wbase, leader);
            int off = __popcll(mask & ((1ull << lane) - 1ull));
            int slot = wbase + off;
            if (slot < SCAP) sp[slot] = make_float2(px, py);
        }
    }
    __syncthreads();

    int n = sn; if (n > SCAP) n = SCAP;
    const int total = n * 49;
    for (int t = tid; t < total; t += THR) {
        int pi = t / 49;
        int c = t - pi * 49;
        float px = sp[pi].x;
        float py = sp[pi].y;
        int ix = (int)floorf(px);
        int iy = (int)floorf(py);
        int dx = c / 7 - RR;
        int dy = c - (c / 7) * 7 - RR;
        int gx = ix + dx, gy = iy + dy;
        if (gx < x0 || gx >= x0 + SH || gy < 0 || gy >= GW) continue;
        float ddx = ((float)gx + 0.5f) - px;
        float ddy = ((float)gy + 0.5f) - py;
        float d2 = ddx * ddx + ddy * ddy;
        float val = expf(-d2 / 4.5f);
        atomicMax(&strip[(gx - x0) * GW + gy], __float_as_int(val));
    }
    __syncthreads();

    float* heat = map ? heat1 : heat0;
    float* hb = heat + (size_t)b * GHW + (size_t)x0 * GW;
    for (int c4 = tid * 4; c4 < SH * GW; c4 += 4 * THR) {
        int4 iv = *reinterpret_cast<const int4*>(&strip[c4]);
        float4 fv;
        fv.x = __int_as_float(iv.x);
        fv.y = __int_as_float(iv.y);
        fv.z = __int_as_float(iv.z);
        fv.w = __int_as_float(iv.w);
        *reinterpret_cast<float4*>(hb + c4) = fv;
    }
}

// LDS-staged gather v2 (requires N%1024==0 && M%1024==0; true here).
// Stage xyz ONLY (12B/pt -> 12KB LDS): pc = direct lane-contiguous f32x4
// copy; radar = 6-vec4 read + xyz compaction (3 vec4 LDS writes / 4 pts).
// 128 threads x 8 pts/thread (strided by 128; stride-3 LDS reads
// conflict-free, 3 coprime 32). Lane-contiguous scalar nt stores (full
// line coverage - no RMW). 12KB/block => ~13 blocks/CU => MLP ~13K
// reads-in-flight/CU, 2.2x R11 (the discriminating variable).
// blockIdx.x == b == linear%8 keeps heat XCD-L2-local.
__global__ __launch_bounds__(GTHR)
void gather_lds_kernel(const float* __restrict__ pc0,
                       const float* __restrict__ pc1,
                       const float* __restrict__ radar0,
                       const float* __restrict__ radar1,
                       const float* __restrict__ pose0,
                       const float* __restrict__ pose1,
                       const float* __restrict__ heat0,
                       const float* __restrict__ heat1,
                       float* __restrict__ out,
                       int N, int M) {
    __shared__ float stage[3 * GCH];   // 12 KB (xyz only)
    __shared__ float Tsh[12];
    const int tid = threadIdx.x;
    const int row_len = 2 * N + 2 * M;
    const int b = blockIdx.x;

    if (tid == 0) compute_pose(pose0 + b * 16, pose1 + b * 16, Tsh);

    const int ncp = N / GCH;
    const int ncr = M / GCH;
    const int c = blockIdx.y;

    const float* segbase;
    const float* T = nullptr;
    const float* hb;
    int stride, out_base, pseg;
    if (c < ncp) {
        segbase = pc0 + (size_t)b * N * 3; stride = 3;
        out_base = 0;          T = Tsh; hb = heat0; pseg = c * GCH;
    } else if (c < ncp + ncr) {
        segbase = radar0 + (size_t)b * M * 6; stride = 6;
        out_base = N;          T = Tsh; hb = heat0; pseg = (c - ncp) * GCH;
    } else if (c < 2 * ncp + ncr) {
        segbase = pc1 + (size_t)b * N * 3; stride = 3;
        out_base = N + M;               hb = heat1; pseg = (c - ncp - ncr) * GCH;
    } else {
        segbase = radar1 + (size_t)b * M * 6; stride = 6;
        out_base = 2 * N + M;           hb = heat1; pseg = (c - 2 * ncp - ncr) * GCH;
    }
    const float* hbb = hb + (size_t)b * GHW;

    // ---- stage chunk xyz -> LDS ----
    if (stride == 3) {
        const f32x4* src = reinterpret_cast<const f32x4*>(
            segbase + (size_t)pseg * 3);
        f32x4* dst = reinterpret_cast<f32x4*>(stage);
        #pragma unroll
        for (int i = tid; i < (3 * GCH) / 4; i += GTHR)   // 768 vec4s, 6 iters
            dst[i] = __builtin_nontemporal_load(src + i);
    } else {
        const f32x4* src = reinterpret_cast<const f32x4*>(
            segbase + (size_t)pseg * 6);
        f32x4* dst = reinterpret_cast<f32x4*>(stage);
        for (int g = tid; g < GCH / 4; g += GTHR) {       // 4-pt groups
            const f32x4* s = src + (size_t)g * 6;
            f32x4 q0 = __builtin_nontemporal_load(s + 0);
            f32x4 q1 = __builtin_nontemporal_load(s + 1);
            f32x4 q2 = __builtin_nontemporal_load(s + 2);
            f32x4 q3 = __builtin_nontemporal_load(s + 3);
            f32x4 q4 = __builtin_nontemporal_load(s + 4);
            f32x4 q5 = __builtin_nontemporal_load(s + 5);
            f32x4 w0; w0.x = q0.x; w0.y = q0.y; w0.z = q0.z; w0.w = q1.z;
            f32x4 w1; w1.x = q1.w; w1.y = q2.x; w1.z = q3.x; w1.w = q3.y;
            f32x4 w2; w2.x = q3.z; w2.y = q4.z; w2.z = q4.w; w2.w = q5.x;
            dst[3 * g + 0] = w0;
            dst[3 * g + 1] = w1;
            dst[3 * g + 2] = w2;
        }
    }
    __syncthreads();

    // ---- compute 8 pts/thread (strided) + lane-contiguous scalar stores ----
    float* ob = out + (size_t)b * row_len + out_base + pseg;
    #pragma unroll
    for (int j = 0; j < GCH / GTHR; j++) {   // 8 iterations
        int k = j * GTHR + tid;
        const float* p = stage + k * 3;
        float px, py; int ix, iy; bool valid;
        voxelize_xyz(p[0], p[1], p[2], T, px, py, ix, iy, valid);
        float v = 0.0f;
        if (valid) v = hbb[ix * GW + iy];
        __builtin_nontemporal_store(v, ob + k);
    }
}

// Scalar fallback gather (general N, M).
__global__ __launch_bounds__(256)
void gather_fused_kernel(const float* __restrict__ pc0,
                         const float* __restrict__ pc1,
                         const float* __restrict__ radar0,
                         const float* __restrict__ radar1,
                         const float* __restrict__ pose0,
                         const float* __restrict__ pose1,
                         const float* __restrict__ heat0,
                         const float* __restrict__ heat1,
                         float* __restrict__ out,
                         int N, int M) {
    __shared__ float Tsh[12];
    const int row_len = 2 * N + 2 * M;
    const int b = blockIdx.x;
    const int base = blockIdx.y * 1024 + threadIdx.x;

    if (threadIdx.x == 0) compute_pose(pose0 + b * 16, pose1 + b * 16, Tsh);
    __syncthreads();

    const float* hb0 = heat0 + (size_t)b * GHW;
    const float* hb1 = heat1 + (size_t)b * GHW;

    #pragma unroll
    for (int k = 0; k < 4; k++) {
        int r = base + k * 256;
        if (r >= row_len) continue;
        const float* p;
        const float* T = nullptr;
        const float* hb;
        if (r < N) {
            p = pc0 + ((size_t)b * N + r) * 3; T = Tsh; hb = hb0;
        } else if (r < N + M) {
            p = radar0 + ((size_t)b * M + (r - N)) * 6; T = Tsh; hb = hb0;
        } else if (r < 2 * N + M) {
            p = pc1 + ((size_t)b * N + (r - N - M)) * 3; hb = hb1;
        } else {
            p = radar1 + ((size_t)b * M + (r - 2 * N - M)) * 6; hb = hb1;
        }
        float px, py; int ix, iy; bool valid;
        voxelize_xyz(p[0], p[1], p[2], T, px, py, ix, iy, valid);
        float v = 0.0f;
        if (valid) v = hb[ix * GW + iy];
        __builtin_nontemporal_store(v, out + (size_t)b * row_len + r);
    }
}

extern "C" void kernel_launch(void* const* d_in, const int* in_sizes, int n_in,
                              void* d_out, int out_size, void* d_ws, size_t ws_size,
                              hipStream_t stream) {
    const float* pc0      = (const float*)d_in[0];
    const float* pc1      = (const float*)d_in[1];
    const float* radar0   = (const float*)d_in[2];
    const float* radar1   = (const float*)d_in[3];
    const float* pose0    = (const float*)d_in[4];
    const float* pose1    = (const float*)d_in[5];
    float* out = (float*)d_out;

    int B = in_sizes[4] / 16;
    int N = in_sizes[0] / (B * 3);
    int M = in_sizes[2] / (B * 6);
    int row_len = 2 * N + 2 * M;

    // workspace layout: just the two heatmaps
    float* heat0 = (float*)d_ws;
    float* heat1 = heat0 + (size_t)B * GHW;

    int nblk = 2 * B * NSTRIP;   // 256 for B=8: 1 block/CU
    heat_strip_kernel<<<nblk, THR, 0, stream>>>(
        radar0, radar1, pose0, pose1, heat0, heat1, B, M);

    if ((N % GCH) == 0 && (M % GCH) == 0) {
        dim3 ggrid(B, 2 * (N / GCH) + 2 * (M / GCH));
        gather_lds_kernel<<<ggrid, GTHR, 0, stream>>>(
            pc0, pc1, radar0, radar1, pose0, pose1, heat0, heat1, out, N, M);
    } else {
        dim3 ggrid(B, (row_len + 1023) / 1024);
        gather_fused_kernel<<<ggrid, 256, 0, stream>>>(
            pc0, pc1, radar0, radar1, pose0, pose1, heat0, heat1, out, N, M);
    }
}